// Round 1
// baseline (552.366 us; speedup 1.0000x reference)
//
#include <hip/hip_runtime.h>
#include <cstdint>

// Problem constants (B, BS, M, D) = (64, 8, 512, 256), neg = B/BS = 8
#define NEG_FILL_F (-10000000000.0f)
constexpr int BB     = 64;
constexpr int BS_    = 8;
constexpr int MM     = 512;
constexpr int DD     = 256;
constexpr int ROWS_X = BB * MM;           // 32768
constexpr int ROWS_Y = BS_ * MM;          // 4096
constexpr int ROWS_ALL = ROWS_X + ROWS_Y; // 36864
constexpr int K3     = 768;               // triple-split K' = 3*DD

typedef __attribute__((ext_vector_type(8))) short short8;   // 8 bf16 = 4 VGPRs
typedef __attribute__((ext_vector_type(4))) float f32x4;    // MFMA C/D

__device__ inline unsigned short rne_bf16(float f) {
    unsigned int u = __float_as_uint(f);
    u = (u + 0x7FFFu + ((u >> 16) & 1u)) >> 16;
    return (unsigned short)u;
}
__device__ inline float bf2f(unsigned short h) {
    return __uint_as_float(((unsigned int)h) << 16);
}

__device__ inline f32x4 mfma16(short8 a, short8 b, f32x4 c) {
    return __builtin_amdgcn_mfma_f32_16x16x32_bf16(a, b, c, 0, 0, 0);
}

// Async global->LDS 16B copy. LDS dst is wave-uniform base; HW adds lane*16.
__device__ inline void gld16(const unsigned short* g, unsigned short* l) {
    __builtin_amdgcn_global_load_lds(
        (const __attribute__((address_space(1))) unsigned int*)g,
        (__attribute__((address_space(3))) unsigned int*)l, 16, 0, 0);
}

__device__ inline void mfma_4x4(const short8 af[4], const short8 bf_[4],
                                f32x4 acc[4][4]) {
    #pragma unroll
    for (int i = 0; i < 4; ++i)
        #pragma unroll
        for (int j = 0; j < 4; ++j)
            acc[i][j] = mfma16(af[i], bf_[j], acc[i][j]);
}

// ---------------------------------------------------------------------------
// Rotation-swizzled staging of a 128-row x 96-bf16 tile (stride-K3 source).
// LDS row r slot q (16B chunks) holds global chunk (q - r) mod 12. This makes
// the stride-192B per-row ds_read_b128 at worst 3-way bank-conflicted (was
// 8-way). Involution pair: read side uses slot (c0 + r) mod 12.
// ---------------------------------------------------------------------------
__device__ inline void stage768_rot(unsigned short* dstbase,
                                    const unsigned short* __restrict__ src,
                                    int ck, int wave, int lane)
{
    #pragma unroll
    for (int s = 0; s < 6; ++s) {
        const int c  = s * 256 + wave * 64 + lane;  // 0..1535
        const int r  = c / 12;
        const int q  = c - r * 12;
        const int rm = r % 12;
        int cin = q - rm;
        cin += (cin >> 31) & 12;                    // mod 12 into [0,12)
        gld16(src + (size_t)r * K3 + ck * 96 + cin * 8,
              dstbase + (size_t)(s * 256 + wave * 64) * 8);
    }
}

// 4 A/B fragments from a rot-96 tile; rows rbase + {0,16,32,48} + lid.
// rm[i] = (rbase + i*16 + lid) % 12 precomputed by caller.
__device__ inline void frag4_rot96(const unsigned short (*T)[96], int rbase,
                                   int lid, const int rm[4], int c0,
                                   short8 f[4])
{
    #pragma unroll
    for (int i = 0; i < 4; ++i) {
        int q = c0 + rm[i];
        if (q >= 12) q -= 12;
        f[i] = *(const short8*)&T[rbase + i * 16 + lid][q * 8];
    }
}

// ---------------------------------------------------------------------------
// W -> Wb: [3][256][768] triple-split B-form (h,h,l). 96 blocks x 256.
// ---------------------------------------------------------------------------
__global__ __launch_bounds__(256) void convw_kernel(
    const float* __restrict__ Wq, const float* __restrict__ Wk,
    const float* __restrict__ Wv, unsigned short* __restrict__ Wb)
{
    const int g  = blockIdx.x * 256 + threadIdx.x;   // < 24576
    const int e  = g * 8;                            // over 3*65536
    const int zi = e >> 16;
    const int off = e & 65535;
    const float* W = (zi == 0) ? Wq : (zi == 1 ? Wk : Wv);
    float4 v0 = *(const float4*)(W + off);
    float4 v1 = *(const float4*)(W + off + 4);
    const float fv[8] = {v0.x, v0.y, v0.z, v0.w, v1.x, v1.y, v1.z, v1.w};
    unsigned short o[24];
    #pragma unroll
    for (int i = 0; i < 8; ++i) {
        unsigned short h = rne_bf16(fv[i]);
        unsigned short l = rne_bf16(fv[i] - bf2f(h));
        o[i*3+0] = h; o[i*3+1] = h; o[i*3+2] = l;
    }
    unsigned short* dst = Wb + (size_t)zi * 196608 + (size_t)off * 3;
    #pragma unroll
    for (int s = 0; s < 3; ++s) {
        short8 v;
        #pragma unroll
        for (int e2 = 0; e2 < 8; ++e2) v[e2] = (short)o[s*8+e2];
        *(short8*)(dst + s * 8) = v;
    }
}

// ---------------------------------------------------------------------------
// x|y -> xs: [36864][768] triple-split A-form (h,l,h). Done ONCE (was 6x
// redundant VALU splitting inside proj). grid = 4608 x 256.
// ---------------------------------------------------------------------------
__global__ __launch_bounds__(256) void convx_kernel(
    const float* __restrict__ x, const float* __restrict__ y,
    unsigned short* __restrict__ xs)
{
    const int g   = blockIdx.x * 256 + threadIdx.x;  // < 1179648
    const int row = g >> 5;                          // 32 threads per 256-row
    const int off = (g & 31) * 8;
    const float* src = (row < ROWS_X) ? (x + (size_t)row * DD)
                                      : (y + (size_t)(row - ROWS_X) * DD);
    float4 v0 = *(const float4*)(src + off);
    float4 v1 = *(const float4*)(src + off + 4);
    const float fv[8] = {v0.x, v0.y, v0.z, v0.w, v1.x, v1.y, v1.z, v1.w};
    unsigned short o[24];
    #pragma unroll
    for (int i = 0; i < 8; ++i) {
        unsigned short h = rne_bf16(fv[i]);
        unsigned short l = rne_bf16(fv[i] - bf2f(h));
        o[i*3+0] = h; o[i*3+1] = l; o[i*3+2] = h;    // A-form
    }
    unsigned short* dst = xs + (size_t)row * K3 + (size_t)off * 3;
    #pragma unroll
    for (int s = 0; s < 3; ++s) {
        short8 w;
        #pragma unroll
        for (int e2 = 0; e2 < 8; ++e2) w[e2] = (short)o[s*8+e2];
        *(short8*)(dst + s * 8) = w;
    }
}

// ---------------------------------------------------------------------------
// Projections via MFMA (K'=768). Both operands async-staged (rot-swizzled).
// z=0 -> Qa (A-form) + plain Qp for x rows; z=1 -> Kb (B-form) + plain Kp for
// y rows; z=2 -> Vt[b][d][j] plain bf16.  grid = (288, 2, 3)
// ---------------------------------------------------------------------------
__global__ __launch_bounds__(256) void proj_kernel(
    const unsigned short* __restrict__ xs,
    const unsigned short* __restrict__ Wb,
    unsigned short* __restrict__ Qa, unsigned short* __restrict__ Kb,
    unsigned short* __restrict__ Vt,
    unsigned short* __restrict__ Qp, unsigned short* __restrict__ Kp)
{
    const int z    = blockIdx.z;
    const int row0 = blockIdx.x * 128;
    const int col0 = blockIdx.y * 128;
    const unsigned short* Asrc = xs + (size_t)row0 * K3;
    const unsigned short* Bsrc = Wb + (size_t)z * 196608 + (size_t)col0 * K3;

    __shared__ unsigned short Ab[128][96];
    __shared__ unsigned short Bb[128][96];

    const int t = threadIdx.x;
    const int wave = t >> 6, lane = t & 63, quad = lane >> 4, lid = lane & 15;
    const int wrow = (wave & 1) * 64, wcol = (wave >> 1) * 64;

    int rma[4], rmb[4];
    #pragma unroll
    for (int i = 0; i < 4; ++i) {
        rma[i] = (wrow + i * 16 + lid) % 12;
        rmb[i] = (wcol + i * 16 + lid) % 12;
    }

    f32x4 acc[4][4];
    #pragma unroll
    for (int i = 0; i < 4; ++i)
        #pragma unroll
        for (int j = 0; j < 4; ++j) acc[i][j] = (f32x4){0.f, 0.f, 0.f, 0.f};

    for (int ck = 0; ck < 8; ++ck) {
        stage768_rot(&Ab[0][0], Asrc, ck, wave, lane);
        stage768_rot(&Bb[0][0], Bsrc, ck, wave, lane);
        __syncthreads();
        #pragma unroll
        for (int kk = 0; kk < 96; kk += 32) {
            const int c0 = (kk >> 3) + quad;
            short8 af[4], bf_[4];
            frag4_rot96(Ab, wrow, lid, rma, c0, af);
            frag4_rot96(Bb, wcol, lid, rmb, c0, bf_);
            mfma_4x4(af, bf_, acc);
        }
        __syncthreads();
    }

    if (z == 2) {
        #pragma unroll
        for (int i = 0; i < 4; ++i) {
            const int rg = row0 + wrow + i * 16 + quad * 4;
            const int b  = rg >> 9;
            const int j  = rg & 511;
            #pragma unroll
            for (int jt = 0; jt < 4; ++jt) {
                const int col = col0 + wcol + jt * 16 + lid;
                *(ushort4*)(Vt + (size_t)b * DD * MM + (size_t)col * MM + j) =
                    make_ushort4(rne_bf16(acc[i][jt][0]), rne_bf16(acc[i][jt][1]),
                                 rne_bf16(acc[i][jt][2]), rne_bf16(acc[i][jt][3]));
            }
        }
    } else {
        unsigned short* dst = (z == 0) ? Qa : Kb;
        const bool aform = (z == 0);
        unsigned short* plain = nullptr;
        int rbase_plain = 0;
        if (z == 0 && row0 < ROWS_X) { plain = Qp; rbase_plain = 0; }
        if (z == 1 && row0 >= ROWS_X) { plain = Kp; rbase_plain = ROWS_X; }
        #pragma unroll
        for (int i = 0; i < 4; ++i) {
            const int rg = row0 + wrow + i * 16 + quad * 4;
            #pragma unroll
            for (int r = 0; r < 4; ++r) {
                unsigned short* rowp = dst + (size_t)(rg + r) * K3;
                unsigned short* prow = plain
                    ? (plain + (size_t)(rg + r - rbase_plain) * DD) : nullptr;
                #pragma unroll
                for (int jt = 0; jt < 4; ++jt) {
                    const int col = col0 + wcol + jt * 16 + lid;
                    const float v = acc[i][jt][r];
                    unsigned short h = rne_bf16(v);
                    unsigned short l = rne_bf16(v - bf2f(h));
                    rowp[3*col+0] = h;
                    rowp[3*col+1] = aform ? l : h;
                    rowp[3*col+2] = aform ? h : l;
                    if (prow) prow[col] = h;
                }
            }
        }
    }
}

// ---------------------------------------------------------------------------
// Self scores (x-self z<64, y-self z>=64) via MFMA K'=768, rot-swizzled
// staging, mask epilogue + fused per-block softmax partials.
// grid = (4, 4, 72). All batch-contiguous buffers, single launch.
// ---------------------------------------------------------------------------
__global__ __launch_bounds__(256) void scores_self_kernel(
    const unsigned short* __restrict__ Qa,
    const unsigned short* __restrict__ Kb,
    const int* __restrict__ mask_x, const int* __restrict__ mask_y,
    float* __restrict__ Sbase, float2* __restrict__ pstats)
{
    const int z    = blockIdx.z;                     // 0..71
    const int row0 = blockIdx.x * 128;
    const int col0 = blockIdx.y * 128;
    const unsigned short* Asrc = Qa + (size_t)(z * MM + row0) * K3;
    const unsigned short* Bsrc = Kb + (size_t)(z * MM + col0) * K3;
    const int* msk = (z < 64) ? (mask_x + z * MM) : (mask_y + (z - 64) * MM);
    float* S = Sbase + (size_t)z * MM * MM;

    __shared__ unsigned short Ab[128][96];
    __shared__ unsigned short Bb[128][96];
    __shared__ float pm2[128][2];
    __shared__ float ps2[128][2];

    const int t = threadIdx.x;
    const int wave = t >> 6, lane = t & 63, quad = lane >> 4, lid = lane & 15;
    const int wrow = (wave & 1) * 64, wcol = (wave >> 1) * 64;

    int rma[4], rmb[4];
    #pragma unroll
    for (int i = 0; i < 4; ++i) {
        rma[i] = (wrow + i * 16 + lid) % 12;
        rmb[i] = (wcol + i * 16 + lid) % 12;
    }

    f32x4 acc[4][4];
    #pragma unroll
    for (int i = 0; i < 4; ++i)
        #pragma unroll
        for (int j = 0; j < 4; ++j) acc[i][j] = (f32x4){0.f, 0.f, 0.f, 0.f};

    for (int ck = 0; ck < 8; ++ck) {
        stage768_rot(&Ab[0][0], Asrc, ck, wave, lane);
        stage768_rot(&Bb[0][0], Bsrc, ck, wave, lane);
        __syncthreads();
        #pragma unroll
        for (int kk = 0; kk < 96; kk += 32) {
            const int c0 = (kk >> 3) + quad;
            short8 af[4], bf_[4];
            frag4_rot96(Ab, wrow, lid, rma, c0, af);
            frag4_rot96(Bb, wcol, lid, rmb, c0, bf_);
            mfma_4x4(af, bf_, acc);
        }
        __syncthreads();
    }

    int mcol[4];
    #pragma unroll
    for (int jt = 0; jt < 4; ++jt) mcol[jt] = msk[col0 + wcol + jt * 16 + lid];

    #pragma unroll
    for (int i = 0; i < 4; ++i) {
        const int rl0 = wrow + i * 16 + quad * 4;
        #pragma unroll
        for (int r = 0; r < 4; ++r) {
            const int rlocal = rl0 + r;
            const int rg = row0 + rlocal;
            const bool mr = (msk[rg] != 0);
            float* Srow = S + (size_t)rg * MM;
            float v[4];
            float mt = -3.4e38f;
            #pragma unroll
            for (int jt = 0; jt < 4; ++jt) {
                const int col = col0 + wcol + jt * 16 + lid;
                const bool valid = mr && (mcol[jt] != 0);
                v[jt] = valid ? acc[i][jt][r] : NEG_FILL_F;
                Srow[col] = v[jt];
                mt = fmaxf(mt, v[jt]);
            }
            #pragma unroll
            for (int o = 1; o < 16; o <<= 1) mt = fmaxf(mt, __shfl_xor(mt, o));
            float se = 0.f;
            #pragma unroll
            for (int jt = 0; jt < 4; ++jt) se += __expf(v[jt] - mt);
            #pragma unroll
            for (int o = 1; o < 16; o <<= 1) se += __shfl_xor(se, o);
            if (lid == 0) { pm2[rlocal][wave >> 1] = mt; ps2[rlocal][wave >> 1] = se; }
        }
    }
    __syncthreads();
    if (t < 128) {
        const float m0 = pm2[t][0], m1 = pm2[t][1];
        const float mm = fmaxf(m0, m1);
        const float ss = ps2[t][0] * __expf(m0 - mm) + ps2[t][1] * __expf(m1 - mm);
        pstats[(size_t)(z * 4 + blockIdx.y) * MM + row0 + t] = make_float2(mm, ss);
    }
}

// ---------------------------------------------------------------------------
// Cross scores (xy) in SINGLE bf16, K=256 (feeds softmax only; ~1e-1 worst
// logit error -> <=~0.1 prob error, below tolerance). XOR-swizzled 64-wide
// tiles (2-way, free). Writes raw scores + mask floats + partials.
// grid = (4, 4, 64)
// ---------------------------------------------------------------------------
__global__ __launch_bounds__(256) void scores_xy_kernel(
    const unsigned short* __restrict__ Qp, const unsigned short* __restrict__ Kp,
    const int* __restrict__ mask_x, const int* __restrict__ mask_y,
    float* __restrict__ Sbase, float* __restrict__ Mbase,
    float2* __restrict__ pstats)
{
    const int z = blockIdx.z;                        // 0..63
    const int n = z >> 3, s = z & 7;
    const int bq = s * 8 + n;                        // x batch
    const int bk = s;                                // y batch
    const int row0 = blockIdx.x * 128;
    const int col0 = blockIdx.y * 128;
    const unsigned short* Asrc = Qp + (size_t)(bq * MM + row0) * DD;
    const unsigned short* Bsrc = Kp + (size_t)(bk * MM + col0) * DD;
    const int* mq = mask_x + bq * MM;
    const int* mk = mask_y + bk * MM;
    float* Sl = Sbase + (size_t)z * MM * MM;
    float* Ml = Mbase + (size_t)z * MM * MM;

    __shared__ unsigned short Ab[128][64];
    __shared__ unsigned short Bb[128][64];
    __shared__ float pm2[128][2];
    __shared__ float ps2[128][2];

    const int t = threadIdx.x;
    const int wave = t >> 6, lane = t & 63, quad = lane >> 4, lid = lane & 15;
    const int wrow = (wave & 1) * 64, wcol = (wave >> 1) * 64;
    const int x7 = lid & 7;

    f32x4 acc[4][4];
    #pragma unroll
    for (int i = 0; i < 4; ++i)
        #pragma unroll
        for (int j = 0; j < 4; ++j) acc[i][j] = (f32x4){0.f, 0.f, 0.f, 0.f};

    for (int ck = 0; ck < 4; ++ck) {
        #pragma unroll
        for (int s4 = 0; s4 < 4; ++s4) {
            const int c   = s4 * 256 + wave * 64 + lane;  // 0..1023
            const int r   = c >> 3;
            const int cin = (c & 7) ^ (r & 7);
            gld16(Asrc + (size_t)r * DD + ck * 64 + cin * 8,
                  &Ab[0][0] + (size_t)(s4 * 256 + wave * 64) * 8);
        }
        #pragma unroll
        for (int s4 = 0; s4 < 4; ++s4) {
            const int c   = s4 * 256 + wave * 64 + lane;
            const int r   = c >> 3;
            const int cin = (c & 7) ^ (r & 7);
            gld16(Bsrc + (size_t)r * DD + ck * 64 + cin * 8,
                  &Bb[0][0] + (size_t)(s4 * 256 + wave * 64) * 8);
        }
        __syncthreads();
        #pragma unroll
        for (int kk = 0; kk < 64; kk += 32) {
            const int c0 = (kk >> 3) + quad;
            const int q  = c0 ^ x7;
            short8 af[4], bf_[4];
            #pragma unroll
            for (int i = 0; i < 4; ++i) {
                af[i]  = *(const short8*)&Ab[wrow + i * 16 + lid][q * 8];
                bf_[i] = *(const short8*)&Bb[wcol + i * 16 + lid][q * 8];
            }
            mfma_4x4(af, bf_, acc);
        }
        __syncthreads();
    }

    int mcol[4];
    #pragma unroll
    for (int jt = 0; jt < 4; ++jt) mcol[jt] = mk[col0 + wcol + jt * 16 + lid];

    #pragma unroll
    for (int i = 0; i < 4; ++i) {
        const int rl0 = wrow + i * 16 + quad * 4;
        #pragma unroll
        for (int r = 0; r < 4; ++r) {
            const int rlocal = rl0 + r;
            const int rg = row0 + rlocal;
            const bool mr = (mq[rg] != 0);
            float* Srow = Sl + (size_t)rg * MM;
            float* Mrow = Ml + (size_t)rg * MM;
            float v[4];
            float mt = -3.4e38f;
            #pragma unroll
            for (int jt = 0; jt < 4; ++jt) {
                const int col = col0 + wcol + jt * 16 + lid;
                const bool valid = mr && (mcol[jt] != 0);
                v[jt] = valid ? acc[i][jt][r] : NEG_FILL_F;
                Srow[col] = v[jt];
                Mrow[col] = valid ? 1.0f : 0.0f;
                mt = fmaxf(mt, v[jt]);
            }
            #pragma unroll
            for (int o = 1; o < 16; o <<= 1) mt = fmaxf(mt, __shfl_xor(mt, o));
            float se = 0.f;
            #pragma unroll
            for (int jt = 0; jt < 4; ++jt) se += __expf(v[jt] - mt);
            #pragma unroll
            for (int o = 1; o < 16; o <<= 1) se += __shfl_xor(se, o);
            if (lid == 0) { pm2[rlocal][wave >> 1] = mt; ps2[rlocal][wave >> 1] = se; }
        }
    }
    __syncthreads();
    if (t < 128) {
        const float m0 = pm2[t][0], m1 = pm2[t][1];
        const float mm = fmaxf(m0, m1);
        const float ss = ps2[t][0] * __expf(m0 - mm) + ps2[t][1] * __expf(m1 - mm);
        pstats[(size_t)(z * 4 + blockIdx.y) * MM + row0 + t] = make_float2(mm, ss);
    }
}

// ---------------------------------------------------------------------------
// Merge 4 col-block partials per row -> (max, 1/sum). grid = 69632/256 = 272.
// Handles x, y, xy contiguously (pstats and stats are laid out batch-major).
// ---------------------------------------------------------------------------
__global__ __launch_bounds__(256) void reduce4_kernel(
    const float2* __restrict__ p, float2* __restrict__ st)
{
    const int row = blockIdx.x * 256 + threadIdx.x;
    const int z = row >> 9, rl = row & 511;
    float m = -3.4e38f, s = 0.f;
    #pragma unroll
    for (int by = 0; by < 4; ++by) {
        float2 v = p[(size_t)(z * 4 + by) * MM + rl];
        float nm = fmaxf(m, v.x);
        s = s * __expf(m - nm) + v.y * __expf(v.x - nm);
        m = nm;
    }
    st[row] = make_float2(m, 1.0f / s);
}

// ---------------------------------------------------------------------------
// Context via MFMA (plain bf16, K'=512). A = exp(S-m) manual-staged (pad 72,
// already 2-way-free); B = Vt async-copied with XOR swizzle (was 16-way
// conflicted). Single launch for x (b<64) and y (b>=64). grid = (4, 2, 72)
// ---------------------------------------------------------------------------
__global__ __launch_bounds__(256) void ctx_kernel(
    const float* __restrict__ Sbase, const float2* __restrict__ stats,
    const unsigned short* __restrict__ Vt_base, float* __restrict__ Obase)
{
    const int b = blockIdx.z;
    const float*          S  = Sbase + (size_t)b * MM * MM;
    const float2*         st = stats + (size_t)b * MM;
    const unsigned short* Vt = Vt_base + (size_t)b * DD * MM;
    float*                O  = Obase + (size_t)b * MM * DD;

    const int row0 = blockIdx.x * 128;
    const int col0 = blockIdx.y * 128;

    __shared__ unsigned short Ab[128][72];
    __shared__ unsigned short Bb[128][64];

    const int t = threadIdx.x;
    const int wave = t >> 6, lane = t & 63, quad = lane >> 4, lid = lane & 15;
    const int wrow = (wave & 1) * 64, wcol = (wave >> 1) * 64;
    const int x7 = lid & 7;

    f32x4 acc[4][4];
    #pragma unroll
    for (int i = 0; i < 4; ++i)
        #pragma unroll
        for (int j = 0; j < 4; ++j) acc[i][j] = (f32x4){0.f, 0.f, 0.f, 0.f};

    for (int ck = 0; ck < 8; ++ck) {
        // B: Vt rows are d (output cols); XOR-swizzled source chunks
        #pragma unroll
        for (int s4 = 0; s4 < 4; ++s4) {
            const int c   = s4 * 256 + wave * 64 + lane;  // 0..1023
            const int r   = c >> 3;
            const int cin = (c & 7) ^ (r & 7);
            gld16(Vt + (size_t)(col0 + r) * MM + ck * 64 + cin * 8,
                  &Bb[0][0] + (size_t)(s4 * 256 + wave * 64) * 8);
        }
        // A: exp(S - m) -> bf16, manual (padded 72: conflict-free already)
        #pragma unroll
        for (int s4 = 0; s4 < 4; ++s4) {
            const int c   = s4 * 256 + t;      // 0..1023
            const int row = c >> 3;
            const int j8  = (c & 7) * 8;
            const float* sp = S + (size_t)(row0 + row) * MM + ck * 64 + j8;
            float4 v0 = *(const float4*)sp;
            float4 v1 = *(const float4*)(sp + 4);
            const float pm = st[row0 + row].x;
            short8 pk;
            pk[0] = (short)rne_bf16(__expf(v0.x - pm));
            pk[1] = (short)rne_bf16(__expf(v0.y - pm));
            pk[2] = (short)rne_bf16(__expf(v0.z - pm));
            pk[3] = (short)rne_bf16(__expf(v0.w - pm));
            pk[4] = (short)rne_bf16(__expf(v1.x - pm));
            pk[5] = (short)rne_bf16(__expf(v1.y - pm));
            pk[6] = (short)rne_bf16(__expf(v1.z - pm));
            pk[7] = (short)rne_bf16(__expf(v1.w - pm));
            *(short8*)&Ab[row][j8] = pk;
        }
        __syncthreads();
        #pragma unroll
        for (int kk = 0; kk < 64; kk += 32) {
            const int c0 = (kk >> 3) + quad;
            const int q  = c0 ^ x7;
            short8 af[4], bf_[4];
            #pragma unroll
            for (int i = 0; i < 4; ++i) {
                af[i]  = *(const short8*)&Ab[wrow + i * 16 + lid][kk + quad * 8];
                bf_[i] = *(const short8*)&Bb[wcol + i * 16 + lid][q * 8];
            }
            mfma_4x4(af, bf_, acc);
        }
        __syncthreads();
    }

    #pragma unroll
    for (int i = 0; i < 4; ++i) {
        const int rgb = row0 + wrow + i * 16 + quad * 4;
        float inv[4];
        #pragma unroll
        for (int r = 0; r < 4; ++r) inv[r] = st[rgb + r].y;
        #pragma unroll
        for (int jt = 0; jt < 4; ++jt) {
            const int col = col0 + wcol + jt * 16 + lid;
            #pragma unroll
            for (int r = 0; r < 4; ++r)
                O[(size_t)(rgb + r) * DD + col] = acc[i][jt][r] * inv[r];
        }
    }
}

// ---------------------------------------------------------------------------
// In-place softmax transform of the scores_xy slot -> probs_xy.
// ---------------------------------------------------------------------------
__global__ __launch_bounds__(128) void softmax_apply(
    float* __restrict__ S, const float2* __restrict__ stats)
{
    const int row = blockIdx.x;
    const float2 st = stats[row];
    float4* r = (float4*)(S + (size_t)row * MM) + threadIdx.x;
    float4 v = *r;
    v.x = __expf(v.x - st.x) * st.y;
    v.y = __expf(v.y - st.x) * st.y;
    v.z = __expf(v.z - st.x) * st.y;
    v.w = __expf(v.w - st.x) * st.y;
    *r = v;
}

// ---------------------------------------------------------------------------
// y_len: one block per s, 64-lane reduce of mask_y[s,:]; lane n<8 writes n*8+s.
// ---------------------------------------------------------------------------
__global__ void ylen_kernel(const int* __restrict__ mask_y, float* __restrict__ out)
{
    const int s = blockIdx.x;
    const int lane = threadIdx.x;
    int c = 0;
    #pragma unroll
    for (int k = 0; k < 8; ++k) c += (mask_y[s * MM + k * 64 + lane] != 0);
    #pragma unroll
    for (int off = 32; off; off >>= 1) c += __shfl_xor(c, off);
    if (lane < 8) out[lane * 8 + s] = (float)c;
}

// ---------------------------------------------------------------------------
extern "C" void kernel_launch(void* const* d_in, const int* in_sizes, int n_in,
                              void* d_out, int out_size, void* d_ws, size_t ws_size,
                              hipStream_t stream)
{
    const float* x      = (const float*)d_in[0];
    const float* y      = (const float*)d_in[1];
    const int*   mask_x = (const int*)d_in[2];
    const int*   mask_y = (const int*)d_in[3];
    const float* Wq     = (const float*)d_in[4];
    const float* Wk     = (const float*)d_in[5];
    const float* Wv     = (const float*)d_in[6];
    float* out = (float*)d_out;

    // Workspace (~136 MB, unchanged): Wb | Qa | Kb | Vt | stats | pstats
    unsigned short* Wb = (unsigned short*)d_ws;            // 3*256*768      = 589824
    unsigned short* Qa = Wb + 589824;                      // 36864*768      = 28311552
    unsigned short* Kb = Qa + 28311552;
    unsigned short* Vt = Kb + 28311552;                    // 72*256*512     = 9437184
    float2* stats_x  = (float2*)(Vt + 9437184);            // 69632 rows contiguous
    float2* stats_xy = stats_x + ROWS_ALL;
    float2* ps_x  = stats_x + (ROWS_ALL + ROWS_X);         // 64*4*512 | 8*4*512 | 64*4*512
    float2* ps_xy = ps_x + (64 + 8) * 4 * 512;

    // Output slots (floats, concatenated in reference return order)
    float* out_ctx_x = out;                 // 64*512*256   = 8388608
    float* out_sx    = out + 9437184;       // 64*512*512   = 16777216  (sy follows)
    float* out_pxy   = out + 28311552;      // 8*8*512*512  = 16777216
    float* out_mxy   = out + 45088768;      // 8*8*512*512  = 16777216
    float* out_ylen  = out + 61865984;      // 8*8          = 64

    // Stream-ordered scratch carved out of d_out (zero extra ws):
    //   xs lives in out_pxy (consumed by proj; pxy written later by scores_xy)
    //   Qp/Kp live in out_ctx (consumed by scores_xy; ctx written after)
    unsigned short* xs = (unsigned short*)out_pxy;         // 36864*768 sh = 56.6 MB < 67 MB
    unsigned short* Qp = (unsigned short*)out_ctx_x;       // 32768*256 sh = 16.8 MB
    unsigned short* Kp = Qp + (size_t)ROWS_X * DD;         //  4096*256 sh, ends < 33.5 MB

    // 1. W -> split B-form; x|y -> split A-form (once)
    convw_kernel<<<96, 256, 0, stream>>>(Wq, Wk, Wv, Wb);
    convx_kernel<<<4608, 256, 0, stream>>>(x, y, xs);

    // 2. Projections (MFMA, both operands async-staged + rot swizzle)
    proj_kernel<<<dim3(288, 2, 3), 256, 0, stream>>>(xs, Wb, Qa, Kb, Vt, Qp, Kp);

    // 3. Scores: self (x+y merged, triple-split) and xy (single bf16, K=256)
    scores_self_kernel<<<dim3(4, 4, 72), 256, 0, stream>>>(
        Qa, Kb, mask_x, mask_y, out_sx, ps_x);
    scores_xy_kernel<<<dim3(4, 4, 64), 256, 0, stream>>>(
        Qp, Kp, mask_x, mask_y, out_pxy, out_mxy, ps_xy);

    // 4. Merge partials -> (max, 1/sum) for all 69632 rows
    reduce4_kernel<<<(ROWS_ALL + ROWS_X) / 256, 256, 0, stream>>>(ps_x, stats_x);

    // 5. Context GEMMs (x+y merged; exp fused on A-stage)
    ctx_kernel<<<dim3(4, 2, 72), 256, 0, stream>>>(out_sx, stats_x, Vt, out_ctx_x);

    // 6. scores_xy -> probs_xy in place
    softmax_apply<<<ROWS_X, 128, 0, stream>>>(out_pxy, stats_xy);

    // 7. y_len
    ylen_kernel<<<8, 64, 0, stream>>>(mask_y, out_ylen);
}